// Round 1
// baseline (323.399 us; speedup 1.0000x reference)
//
#include <hip/hip_runtime.h>

// Problem constants
#define NN 64
#define CC 64
#define TT 256
#define VV 25
#define RR 8
#define OO 64
#define PLANE 6400  // T*V per (n,c)
#define SX 226      // x3s row stride in floats; 226 % 32 == 2 -> phase-2 LDS
                    // reads land 2 lanes/bank (free, m136)

// ---------------------------------------------------------------------------
// Kernel A: xsum[n][c][v] = sum_t x[n][c][t][v]
// One block per (n,c). Stage the 6400-float plane in LDS coalesced, reduce.
// Blocks 0..15 additionally transpose w3 -> w3t (folds old k_wt launch).
// ---------------------------------------------------------------------------
__global__ __launch_bounds__(256) void k_xsum(const float* __restrict__ x,
                                              float* __restrict__ xsum,
                                              const float* __restrict__ w3,
                                              float* __restrict__ w3t) {
  int nc = blockIdx.x;  // n*64 + c
  int tid = threadIdx.x;
  if (blockIdx.x < 16) {
    int k = blockIdx.x * 256 + tid;  // < 4096
    int c = k >> 6, o = k & 63;
    w3t[k] = w3[o * 64 + c];
  }
  const float* src = x + (size_t)nc * PLANE;
  __shared__ float s[PLANE];
#pragma unroll
  for (int k = 0; k < 25; ++k) s[k * 256 + tid] = src[k * 256 + tid];
  __syncthreads();
  if (tid < VV) {
    float a0 = 0.f, a1 = 0.f, a2 = 0.f, a3 = 0.f;
    for (int t = 0; t < TT; t += 4) {
      a0 += s[(t + 0) * VV + tid];
      a1 += s[(t + 1) * VV + tid];
      a2 += s[(t + 2) * VV + tid];
      a3 += s[(t + 3) * VV + tid];
    }
    xsum[nc * VV + tid] = (a0 + a1) + (a2 + a3);
  }
}

// ---------------------------------------------------------------------------
// Kernel B: build m, TRANSPOSED + padded: mp[n][o][v][32] holds m[n,o,u,v] at
// word u. v-major rows so the fused kernel can float4-load m[o][:,v].
// Grid (n, og): each block computes 16 o's (4x parallelism vs before;
// x1/x2/att recomputed per group -- cheap).
// ---------------------------------------------------------------------------
__global__ __launch_bounds__(256) void k_build_m(
    const float* __restrict__ xsum, const float* __restrict__ A,
    const float* __restrict__ w1, const float* __restrict__ b1,
    const float* __restrict__ w2, const float* __restrict__ b2,
    const float* __restrict__ w4, const float* __restrict__ b4,
    float* __restrict__ mp) {
  int n = blockIdx.x;
  int og = blockIdx.y;             // o-group: o in [og*16, og*16+16)
  __shared__ float xs[CC * VV];    // 1600
  __shared__ float sx1[RR * VV];   // 200
  __shared__ float sx2[RR * VV];   // 200
  __shared__ float att[RR * 625];  // 5000
  int tid = threadIdx.x;
  const float* xsn = xsum + n * (CC * VV);
  for (int k = tid; k < CC * VV; k += 256) xs[k] = xsn[k];
  __syncthreads();
  if (tid < RR * VV) {
    int r = tid / VV, v = tid % VV;
    float a1 = 0.f, a2 = 0.f;
#pragma unroll
    for (int c = 0; c < CC; ++c) {
      float xv = xs[c * VV + v];
      a1 = fmaf(w1[r * CC + c], xv, a1);
      a2 = fmaf(w2[r * CC + c], xv, a2);
    }
    sx1[tid] = a1 * (1.f / 256.f) + b1[r];
    sx2[tid] = a2 * (1.f / 256.f) + b2[r];
  }
  __syncthreads();
  for (int k = tid; k < RR * 625; k += 256) {
    int r = k / 625, uv = k % 625;
    int u = uv / VV, v = uv % VV;
    att[k] = tanhf(sx1[r * VV + u] - sx2[r * VV + v]);
  }
  __syncthreads();
  // v-major emission: consecutive lanes sweep u -> coalesced stores; att reads
  // stride 25 (gcd(25,32)=1 -> conflict-free).
  for (int k = tid; k < 16 * 625; k += 256) {
    int o = og * 16 + k / 625, vu = k % 625;
    int v = vu / VV, u = vu % VV;
    float a = b4[o] + A[u * VV + v];
#pragma unroll
    for (int r = 0; r < RR; ++r)
      a = fmaf(w4[o * RR + r], att[r * 625 + u * VV + v], a);
    mp[(((size_t)n * OO + o) * VV + v) * 32 + u] = a;
  }
}

// ---------------------------------------------------------------------------
// Kernel F (fused conv3 + aggregation): block = (t-tile of 8 rows, n).
// Phase 1: 200 lanes (t_sub,v) compute x3[o][t][v] for all 64 o in registers
//          (64 coalesced 800B x loads, wave-uniform w3t s_loads), park in LDS.
// Phase 2: lane (o=tid>>2, tq=tid&3) computes out rows t=tq,tq+4, all 25 u:
//          per v: one contiguous m row (float4, L2-resident) x 2 LDS scalars
//          -> 50 FMA. t-pair {tq,tq+4} + stride 226 => 2 lanes/bank (free).
// Phase 3: acc -> LDS -> coalesced [64][200] tile store (direct stores would
//          scatter 4B across 16 o-planes per instruction).
// Eliminates the 210 MB x3 HBM round trip of the split version.
// ---------------------------------------------------------------------------
__global__ __launch_bounds__(256, 2) void k_fused(
    const float* __restrict__ x, const float* __restrict__ w3t,
    const float* __restrict__ b3, const float* __restrict__ mp,
    float* __restrict__ out) {
  int n = blockIdx.y;
  int t0 = blockIdx.x * 8;  // 32 tiles of 8 t-rows
  __shared__ float s[OO * SX];  // 57,856 B -> 2 blocks/CU
  int tid = threadIdx.x;

  // ---- phase 1: conv3 for this tile's 200 points, all 64 o
  if (tid < 200) {
    const float* xp = x + (size_t)n * CC * PLANE + t0 * VV + tid;
    float acc[OO];
#pragma unroll
    for (int o = 0; o < OO; ++o) acc[o] = b3[o];
#pragma unroll 2
    for (int c = 0; c < CC; ++c) {
      float xv = xp[(size_t)c * PLANE];
      const float* w = w3t + c * OO;
#pragma unroll
      for (int o = 0; o < OO; ++o) acc[o] = fmaf(w[o], xv, acc[o]);
    }
#pragma unroll
    for (int o = 0; o < OO; ++o) s[o * SX + tid] = acc[o];  // consecutive tid
  }
  __syncthreads();

  // ---- phase 2: out[t][u] = sum_v m[o][u][v] * x3[o][t][v]
  {
    int o = tid >> 2, tq = tid & 3;
    const float* xA = s + o * SX + tq * VV;   // t = tq
    const float* xB = xA + 4 * VV;            // t = tq + 4
    const float* mb = mp + (size_t)(n * OO + o) * VV * 32;
    float accA[VV], accB[VV];
#pragma unroll
    for (int u = 0; u < VV; ++u) {
      accA[u] = 0.f;
      accB[u] = 0.f;
    }
#pragma unroll 2
    for (int v = 0; v < VV; ++v) {
      float xa = xA[v];
      float xb = xB[v];
      const float* mr = mb + v * 32;  // 128B-aligned row, u=0..24
#pragma unroll
      for (int u = 0; u < VV; ++u) {
        float mv = mr[u];
        accA[u] = fmaf(mv, xa, accA[u]);
        accB[u] = fmaf(mv, xb, accB[u]);
      }
    }
    __syncthreads();  // all x3 reads done; reuse s as the out tile
#pragma unroll
    for (int u = 0; u < VV; ++u) {
      s[o * SX + tq * VV + u] = accA[u];
      s[o * SX + (tq + 4) * VV + u] = accB[u];
    }
  }
  __syncthreads();

  // ---- phase 3: coalesced store of the [64 o][200 p] tile
  float* ob = out + (size_t)n * OO * PLANE + t0 * VV;
  for (int k = tid; k < OO * 200; k += 256) {
    int oo = k / 200, p = k - oo * 200;
    ob[(size_t)oo * PLANE + p] = s[oo * SX + p];
  }
}

extern "C" void kernel_launch(void* const* d_in, const int* in_sizes, int n_in,
                              void* d_out, int out_size, void* d_ws,
                              size_t ws_size, hipStream_t stream) {
  const float* x = (const float*)d_in[0];
  const float* A = (const float*)d_in[1];
  const float* w1 = (const float*)d_in[2];
  const float* b1 = (const float*)d_in[3];
  const float* w2 = (const float*)d_in[4];
  const float* b2 = (const float*)d_in[5];
  const float* w3 = (const float*)d_in[6];
  const float* b3 = (const float*)d_in[7];
  const float* w4 = (const float*)d_in[8];
  const float* b4 = (const float*)d_in[9];
  float* out = (float*)d_out;
  float* ws = (float*)d_ws;

  float* xsum = ws;            // 64*64*25      = 102400 floats
  float* w3t = ws + 102400;    // 4096 floats
  float* mp = ws + 106496;     // 64*64*25*32   = 3276800 floats (13.5 MB total)

  k_xsum<<<NN * CC, 256, 0, stream>>>(x, xsum, w3, w3t);
  k_build_m<<<dim3(NN, 4), 256, 0, stream>>>(xsum, A, w1, b1, w2, b2, w4, b4,
                                             mp);
  k_fused<<<dim3(TT / 8, NN), 256, 0, stream>>>(x, w3t, b3, mp, out);
}

// Round 2
// 317.344 us; speedup vs baseline: 1.0191x; 1.0191x over previous
//
#include <hip/hip_runtime.h>

// Problem constants
#define NN 64
#define CC 64
#define TT 256
#define VV 25
#define RR 8
#define OO 64
#define PLANE 6400  // T*V per (n,c)
#define SX 201      // x3s row stride (floats). 64*201*4 = 51456B -> 3 blocks/CU.
                    // 201 % 32 == 9 (odd) -> phase-2 access patterns <=2-way.

// ---------------------------------------------------------------------------
// Kernel A: xsum[n][c][v] = sum_t x[n][c][t][v]
// One block per (n,c). Stage plane in LDS coalesced; 200-lane reduction
// (tg,v) sums 32 t's each, then 25-lane tail sums 8 partials (was: 25 lanes
// x 256 serial adds -> latency tail).
// Blocks 0..15 additionally transpose w3 -> w3t.
// ---------------------------------------------------------------------------
__global__ __launch_bounds__(256) void k_xsum(const float* __restrict__ x,
                                              float* __restrict__ xsum,
                                              const float* __restrict__ w3,
                                              float* __restrict__ w3t) {
  int nc = blockIdx.x;  // n*64 + c
  int tid = threadIdx.x;
  if (blockIdx.x < 16) {
    int k = blockIdx.x * 256 + tid;  // < 4096
    int c = k >> 6, o = k & 63;
    w3t[k] = w3[o * 64 + c];
  }
  const float* src = x + (size_t)nc * PLANE;
  __shared__ float s[PLANE + 256];
#pragma unroll
  for (int k = 0; k < 25; ++k) s[k * 256 + tid] = src[k * 256 + tid];
  __syncthreads();
  if (tid < 200) {
    int tg = tid / 25, v = tid - tg * 25;
    float a0 = 0.f, a1 = 0.f, a2 = 0.f, a3 = 0.f;
    for (int k = 0; k < 32; k += 4) {
      a0 += s[(tg + 8 * (k + 0)) * VV + v];
      a1 += s[(tg + 8 * (k + 1)) * VV + v];
      a2 += s[(tg + 8 * (k + 2)) * VV + v];
      a3 += s[(tg + 8 * (k + 3)) * VV + v];
    }
    s[PLANE + tid] = (a0 + a1) + (a2 + a3);
  }
  __syncthreads();
  if (tid < VV) {
    float a = 0.f;
#pragma unroll
    for (int g = 0; g < 8; ++g) a += s[PLANE + g * VV + tid];
    xsum[nc * VV + tid] = a;
  }
}

// ---------------------------------------------------------------------------
// Kernel B: build m, layout mp[n][o][v][32] with word u = m[n,o,u,v]
// (v-major rows so the fused kernel float4-loads u-chunks per (o,v)).
// Grid (n, og): each block computes 16 o's.
// ---------------------------------------------------------------------------
__global__ __launch_bounds__(256) void k_build_m(
    const float* __restrict__ xsum, const float* __restrict__ A,
    const float* __restrict__ w1, const float* __restrict__ b1,
    const float* __restrict__ w2, const float* __restrict__ b2,
    const float* __restrict__ w4, const float* __restrict__ b4,
    float* __restrict__ mp) {
  int n = blockIdx.x;
  int og = blockIdx.y;             // o-group: o in [og*16, og*16+16)
  __shared__ float xs[CC * VV];    // 1600
  __shared__ float sx1[RR * VV];   // 200
  __shared__ float sx2[RR * VV];   // 200
  __shared__ float att[RR * 625];  // 5000
  int tid = threadIdx.x;
  const float* xsn = xsum + n * (CC * VV);
  for (int k = tid; k < CC * VV; k += 256) xs[k] = xsn[k];
  __syncthreads();
  if (tid < RR * VV) {
    int r = tid / VV, v = tid % VV;
    float a1 = 0.f, a2 = 0.f;
#pragma unroll
    for (int c = 0; c < CC; ++c) {
      float xv = xs[c * VV + v];
      a1 = fmaf(w1[r * CC + c], xv, a1);
      a2 = fmaf(w2[r * CC + c], xv, a2);
    }
    sx1[tid] = a1 * (1.f / 256.f) + b1[r];
    sx2[tid] = a2 * (1.f / 256.f) + b2[r];
  }
  __syncthreads();
  for (int k = tid; k < RR * 625; k += 256) {
    int r = k / 625, uv = k % 625;
    int u = uv / VV, v = uv % VV;
    att[k] = tanhf(sx1[r * VV + u] - sx2[r * VV + v]);
  }
  __syncthreads();
  // v-major emission: word u of row v holds m[o][u][v].
  for (int k = tid; k < 16 * 625; k += 256) {
    int o = og * 16 + k / 625, vu = k % 625;
    int v = vu / VV, u = vu % VV;
    float a = b4[o] + A[u * VV + v];
#pragma unroll
    for (int r = 0; r < RR; ++r)
      a = fmaf(w4[o * RR + r], att[r * 625 + u * VV + v], a);
    mp[(((size_t)n * OO + o) * VV + v) * 32 + u] = a;
  }
}

// ---------------------------------------------------------------------------
// Kernel F (fused conv3 + aggregation): block = (t-tile of 8 rows, n).
// Phase 1: 200 lanes (t_sub,v) compute x3[o][t][v] for all 64 o (8-deep
//          explicit global prefetch), park in LDS s[o][p], p = t*25+v.
// Phase 2: lane (o = tid>>2, uq = tid&3) owns u-slots uq*8..uq*8+7 for ALL
//          8 t rows (acc[8][8]).  m loads: 2x float4 per v -> per wave-instr
//          16 full 128B rows, fully coalesced (fixes round-1's 16-way 16B
//          scatter = ~37us of TA serialization).  x3 via quad-broadcast LDS
//          reads (banks 9*o+c, conflict-free).  u>=25 pad lanes masked at
//          the writeback.
// Phase 3: acc -> LDS -> coalesced [64 o][200 p] tile store.
// ---------------------------------------------------------------------------
__global__ __launch_bounds__(256, 3) void k_fused(
    const float* __restrict__ x, const float* __restrict__ w3t,
    const float* __restrict__ b3, const float* __restrict__ mp,
    float* __restrict__ out) {
  int n = blockIdx.y;
  int t0 = blockIdx.x * 8;      // 32 tiles of 8 t-rows
  __shared__ float s[OO * SX];  // 51456 B -> 3 blocks/CU
  int tid = threadIdx.x;

  // ---- phase 1: conv3 for this tile's 200 points, all 64 o
  if (tid < 200) {
    const float* xp = x + (size_t)n * CC * PLANE + t0 * VV + tid;
    float acc[OO];
#pragma unroll
    for (int o = 0; o < OO; ++o) acc[o] = b3[o];
    for (int c = 0; c < CC; c += 8) {
      float xv[8];
#pragma unroll
      for (int j = 0; j < 8; ++j) xv[j] = xp[(size_t)(c + j) * PLANE];
#pragma unroll
      for (int j = 0; j < 8; ++j) {
        const float* w = w3t + (c + j) * OO;
#pragma unroll
        for (int o = 0; o < OO; ++o) acc[o] = fmaf(w[o], xv[j], acc[o]);
      }
    }
#pragma unroll
    for (int o = 0; o < OO; ++o) s[o * SX + tid] = acc[o];  // consecutive tid
  }
  __syncthreads();

  // ---- phase 2: out[t][u] = sum_v m[o][u][v] * x3[o][t][v]
  {
    int o = tid >> 2, uq = tid & 3;
    const float* mb = mp + (size_t)(n * OO + o) * (VV * 32) + uq * 8;
    const float* xb = s + o * SX;
    float acc[8][8];
#pragma unroll
    for (int t = 0; t < 8; ++t)
#pragma unroll
      for (int j = 0; j < 8; ++j) acc[t][j] = 0.f;
#pragma unroll 2
    for (int v = 0; v < VV; ++v) {
      float4 m0 = *(const float4*)(mb + v * 32);
      float4 m1 = *(const float4*)(mb + v * 32 + 4);
      float xt[8];
#pragma unroll
      for (int t = 0; t < 8; ++t) xt[t] = xb[t * VV + v];
#pragma unroll
      for (int t = 0; t < 8; ++t) {
        acc[t][0] = fmaf(m0.x, xt[t], acc[t][0]);
        acc[t][1] = fmaf(m0.y, xt[t], acc[t][1]);
        acc[t][2] = fmaf(m0.z, xt[t], acc[t][2]);
        acc[t][3] = fmaf(m0.w, xt[t], acc[t][3]);
        acc[t][4] = fmaf(m1.x, xt[t], acc[t][4]);
        acc[t][5] = fmaf(m1.y, xt[t], acc[t][5]);
        acc[t][6] = fmaf(m1.z, xt[t], acc[t][6]);
        acc[t][7] = fmaf(m1.w, xt[t], acc[t][7]);
      }
    }
    __syncthreads();  // all phase-2 x3 reads done; reuse s as the out tile
#pragma unroll
    for (int t = 0; t < 8; ++t)
#pragma unroll
      for (int j = 0; j < 8; ++j) {
        int u = uq * 8 + j;
        if (u < VV) s[o * SX + t * VV + u] = acc[t][j];
      }
  }
  __syncthreads();

  // ---- phase 3: coalesced store of the [64 o][200 p] tile
  float* ob = out + (size_t)n * OO * PLANE + t0 * VV;
  for (int k = tid; k < OO * 200; k += 256) {
    int oo = k / 200, p = k - oo * 200;
    ob[(size_t)oo * PLANE + p] = s[oo * SX + p];
  }
}

extern "C" void kernel_launch(void* const* d_in, const int* in_sizes, int n_in,
                              void* d_out, int out_size, void* d_ws,
                              size_t ws_size, hipStream_t stream) {
  const float* x = (const float*)d_in[0];
  const float* A = (const float*)d_in[1];
  const float* w1 = (const float*)d_in[2];
  const float* b1 = (const float*)d_in[3];
  const float* w2 = (const float*)d_in[4];
  const float* b2 = (const float*)d_in[5];
  const float* w3 = (const float*)d_in[6];
  const float* b3 = (const float*)d_in[7];
  const float* w4 = (const float*)d_in[8];
  const float* b4 = (const float*)d_in[9];
  float* out = (float*)d_out;
  float* ws = (float*)d_ws;

  float* xsum = ws;            // 64*64*25      = 102400 floats
  float* w3t = ws + 102400;    // 4096 floats
  float* mp = ws + 106496;     // 64*64*25*32   = 3276800 floats (13.5 MB total)

  k_xsum<<<NN * CC, 256, 0, stream>>>(x, xsum, w3, w3t);
  k_build_m<<<dim3(NN, 4), 256, 0, stream>>>(xsum, A, w1, b1, w2, b2, w4, b4,
                                             mp);
  k_fused<<<dim3(TT / 8, NN), 256, 0, stream>>>(x, w3t, b3, mp, out);
}

// Round 4
// 305.036 us; speedup vs baseline: 1.0602x; 1.0404x over previous
//
#include <hip/hip_runtime.h>

// Problem constants
#define NN 64
#define CC 64
#define TT 256
#define VV 25
#define RR 8
#define OO 64
#define PLANE 6400  // T*V per (n,c)
#define SX 101      // x3s row stride (floats). 64*101*4 = 25856B -> 6 blocks/CU
                    // (LDS-granule 26112B*6 = 156.7KB <= 160KB). 101%32 = 5
                    // (odd) -> all phase-2/3 patterns <=2-way bank aliasing.

// NOTE: round-3 submission failed on container acquisition (infra), not on
// the kernel; this is a resubmission of the same source.

// ---------------------------------------------------------------------------
// Kernel A: xsum[n][c][v] = sum_t x[n][c][t][v]
// One block per (n,c). float4-stage the 6400-float plane into LDS (7 wide
// loads vs 25 scalar), then 200-lane tree reduction. Blocks 0..15 also
// transpose w3 -> w3t.
// ---------------------------------------------------------------------------
__global__ __launch_bounds__(256) void k_xsum(const float* __restrict__ x,
                                              float* __restrict__ xsum,
                                              const float* __restrict__ w3,
                                              float* __restrict__ w3t) {
  int nc = blockIdx.x;  // n*64 + c
  int tid = threadIdx.x;
  if (blockIdx.x < 16) {
    int k = blockIdx.x * 256 + tid;  // < 4096
    int c = k >> 6, o = k & 63;
    w3t[k] = w3[o * 64 + c];
  }
  const float4* src4 = (const float4*)(x + (size_t)nc * PLANE);
  __shared__ __align__(16) float s[PLANE + 256];
  float4* s4 = (float4*)s;
  for (int k = tid; k < PLANE / 4; k += 256) s4[k] = src4[k];
  __syncthreads();
  if (tid < 200) {
    int tg = tid / 25, v = tid - tg * 25;
    float a0 = 0.f, a1 = 0.f, a2 = 0.f, a3 = 0.f;
    for (int k = 0; k < 32; k += 4) {
      a0 += s[(tg + 8 * (k + 0)) * VV + v];
      a1 += s[(tg + 8 * (k + 1)) * VV + v];
      a2 += s[(tg + 8 * (k + 2)) * VV + v];
      a3 += s[(tg + 8 * (k + 3)) * VV + v];
    }
    s[PLANE + tid] = (a0 + a1) + (a2 + a3);
  }
  __syncthreads();
  if (tid < VV) {
    float a = 0.f;
#pragma unroll
    for (int g = 0; g < 8; ++g) a += s[PLANE + g * VV + tid];
    xsum[nc * VV + tid] = a;
  }
}

// ---------------------------------------------------------------------------
// Kernel B: build m, layout mp[n][o][v][32] with word u = m[n,o,u,v]
// (v-major rows so the fused kernel float4-loads u-chunks per (o,v)).
// Grid (n, og): each block computes 8 o's (more TLP; att recompute is cheap).
// ---------------------------------------------------------------------------
__global__ __launch_bounds__(256) void k_build_m(
    const float* __restrict__ xsum, const float* __restrict__ A,
    const float* __restrict__ w1, const float* __restrict__ b1,
    const float* __restrict__ w2, const float* __restrict__ b2,
    const float* __restrict__ w4, const float* __restrict__ b4,
    float* __restrict__ mp) {
  int n = blockIdx.x;
  int og = blockIdx.y;             // o-group: o in [og*8, og*8+8)
  __shared__ float xs[CC * VV];    // 1600
  __shared__ float sx1[RR * VV];   // 200
  __shared__ float sx2[RR * VV];   // 200
  __shared__ float att[RR * 625];  // 5000
  int tid = threadIdx.x;
  const float* xsn = xsum + n * (CC * VV);
  for (int k = tid; k < CC * VV; k += 256) xs[k] = xsn[k];
  __syncthreads();
  if (tid < RR * VV) {
    int r = tid / VV, v = tid % VV;
    float a1 = 0.f, a2 = 0.f;
#pragma unroll
    for (int c = 0; c < CC; ++c) {
      float xv = xs[c * VV + v];
      a1 = fmaf(w1[r * CC + c], xv, a1);
      a2 = fmaf(w2[r * CC + c], xv, a2);
    }
    sx1[tid] = a1 * (1.f / 256.f) + b1[r];
    sx2[tid] = a2 * (1.f / 256.f) + b2[r];
  }
  __syncthreads();
  for (int k = tid; k < RR * 625; k += 256) {
    int r = k / 625, uv = k % 625;
    int u = uv / VV, v = uv % VV;
    att[k] = tanhf(sx1[r * VV + u] - sx2[r * VV + v]);
  }
  __syncthreads();
  // v-major emission: word u of row v holds m[o][u][v].
  for (int k = tid; k < 8 * 625; k += 256) {
    int o = og * 8 + k / 625, vu = k % 625;
    int v = vu / VV, u = vu % VV;
    float a = b4[o] + A[u * VV + v];
#pragma unroll
    for (int r = 0; r < RR; ++r)
      a = fmaf(w4[o * RR + r], att[r * 625 + u * VV + v], a);
    mp[(((size_t)n * OO + o) * VV + v) * 32 + u] = a;
  }
}

// ---------------------------------------------------------------------------
// conv_half: phase-1 helper for o in [O0, O0+32). O0 is a TEMPLATE constant
// so w3t/b3 addresses stay provably wave-uniform -> s_load_dwordx16 weights
// (a runtime O0 derived from tid would demote 2048 scalar loads to VMEM).
// Called by waves 0-1 with O0=0 and waves 2-3 with O0=32; each half's 100
// active lanes (p = tid&127 < 100) compute all 64 c for its 32 o's. The two
// halves read identical x lines back-to-back -> L1 absorbs the 2nd read.
// ---------------------------------------------------------------------------
template <int O0>
__device__ __forceinline__ void conv_half(const float* __restrict__ xb,
                                          const float* __restrict__ w3t,
                                          const float* __restrict__ b3,
                                          float* __restrict__ s) {
  int p = threadIdx.x & 127;
  if (p >= 100) return;  // no barriers inside -> divergent return is safe
  const float* xp = xb + p;
  float acc[32];
#pragma unroll
  for (int o = 0; o < 32; ++o) acc[o] = b3[O0 + o];
  for (int c = 0; c < CC; c += 8) {
    float xv[8];
#pragma unroll
    for (int j = 0; j < 8; ++j) xv[j] = xp[(size_t)(c + j) * PLANE];
#pragma unroll
    for (int j = 0; j < 8; ++j) {
      const float* w = w3t + (c + j) * OO + O0;
#pragma unroll
      for (int o = 0; o < 32; ++o) acc[o] = fmaf(w[o], xv[j], acc[o]);
    }
  }
#pragma unroll
  for (int o = 0; o < 32; ++o) s[(O0 + o) * SX + p] = acc[o];
}

// ---------------------------------------------------------------------------
// Kernel F (fused conv3 + aggregation): block = (t-tile of 4 rows, n).
// Round-2 post-mortem: VALU issue (~50us) is at the fp32-FMA floor; the 83us
// gap was latency stall at 3 blocks/CU lockstep. This version halves LDS
// (SX 201->101, t-tile 8->4) for 6 blocks/CU and 16 blocks/CU queued, so
// staggered blocks fill each other's memory stalls.
// Phase 1: wave-pair per o-half, 100 points each (conv_half above).
// Phase 2: lane (o = tid>>2, uq = tid&3) owns u-slots uq*8.., all 4 t rows;
//          m via 2x float4 per v (coalesced 128B rows, L2-resident).
// Phase 3: acc -> LDS -> coalesced [64 o][100 p] tile store.
// ---------------------------------------------------------------------------
__global__ __launch_bounds__(256, 6) void k_fused(
    const float* __restrict__ x, const float* __restrict__ w3t,
    const float* __restrict__ b3, const float* __restrict__ mp,
    float* __restrict__ out) {
  int n = blockIdx.y;
  int t0 = blockIdx.x * 4;      // 64 tiles of 4 t-rows
  __shared__ float s[OO * SX];  // 25856 B -> 6 blocks/CU
  int tid = threadIdx.x;

  // ---- phase 1: conv3 for this tile's 100 points, all 64 o
  const float* xb = x + (size_t)n * CC * PLANE + t0 * VV;
  if (tid < 128)
    conv_half<0>(xb, w3t, b3, s);
  else
    conv_half<32>(xb, w3t, b3, s);
  __syncthreads();

  // ---- phase 2: out[t][u] = sum_v m[o][u][v] * x3[o][t][v]
  {
    int o = tid >> 2, uq = tid & 3;
    const float* mb = mp + (size_t)(n * OO + o) * (VV * 32) + uq * 8;
    const float* xr = s + o * SX;
    float acc[4][8];
#pragma unroll
    for (int t = 0; t < 4; ++t)
#pragma unroll
      for (int j = 0; j < 8; ++j) acc[t][j] = 0.f;
#pragma unroll 2
    for (int v = 0; v < VV; ++v) {
      float4 m0 = *(const float4*)(mb + v * 32);
      float4 m1 = *(const float4*)(mb + v * 32 + 4);
      float xt[4];
#pragma unroll
      for (int t = 0; t < 4; ++t) xt[t] = xr[t * VV + v];
#pragma unroll
      for (int t = 0; t < 4; ++t) {
        acc[t][0] = fmaf(m0.x, xt[t], acc[t][0]);
        acc[t][1] = fmaf(m0.y, xt[t], acc[t][1]);
        acc[t][2] = fmaf(m0.z, xt[t], acc[t][2]);
        acc[t][3] = fmaf(m0.w, xt[t], acc[t][3]);
        acc[t][4] = fmaf(m1.x, xt[t], acc[t][4]);
        acc[t][5] = fmaf(m1.y, xt[t], acc[t][5]);
        acc[t][6] = fmaf(m1.z, xt[t], acc[t][6]);
        acc[t][7] = fmaf(m1.w, xt[t], acc[t][7]);
      }
    }
    __syncthreads();  // all phase-2 x3 reads done; reuse s as the out tile
#pragma unroll
    for (int t = 0; t < 4; ++t)
#pragma unroll
      for (int j = 0; j < 8; ++j) {
        int u = uq * 8 + j;
        if (u < VV) s[o * SX + t * VV + u] = acc[t][j];
      }
  }
  __syncthreads();

  // ---- phase 3: coalesced store of the [64 o][100 p] tile
  float* ob = out + (size_t)n * OO * PLANE + t0 * VV;
  for (int k = tid; k < OO * 100; k += 256) {
    int oo = k / 100, p = k - oo * 100;
    ob[(size_t)oo * PLANE + p] = s[oo * SX + p];
  }
}

extern "C" void kernel_launch(void* const* d_in, const int* in_sizes, int n_in,
                              void* d_out, int out_size, void* d_ws,
                              size_t ws_size, hipStream_t stream) {
  const float* x = (const float*)d_in[0];
  const float* A = (const float*)d_in[1];
  const float* w1 = (const float*)d_in[2];
  const float* b1 = (const float*)d_in[3];
  const float* w2 = (const float*)d_in[4];
  const float* b2 = (const float*)d_in[5];
  const float* w3 = (const float*)d_in[6];
  const float* b3 = (const float*)d_in[7];
  const float* w4 = (const float*)d_in[8];
  const float* b4 = (const float*)d_in[9];
  float* out = (float*)d_out;
  float* ws = (float*)d_ws;

  float* xsum = ws;            // 64*64*25      = 102400 floats
  float* w3t = ws + 102400;    // 4096 floats
  float* mp = ws + 106496;     // 64*64*25*32   = 3276800 floats (13.5 MB total)

  k_xsum<<<NN * CC, 256, 0, stream>>>(x, xsum, w3, w3t);
  k_build_m<<<dim3(NN, 8), 256, 0, stream>>>(xsum, A, w1, b1, w2, b2, w4, b4,
                                             mp);
  k_fused<<<dim3(TT / 4, NN), 256, 0, stream>>>(x, w3t, b3, mp, out);
}

// Round 6
// 293.442 us; speedup vs baseline: 1.1021x; 1.0395x over previous
//
#include <hip/hip_runtime.h>

// Problem constants
#define NN 64
#define CC 64
#define TT 256
#define VV 25
#define RR 8
#define OO 64
#define PLANE 6400  // T*V per (n,c)
#define SX 101      // x3s row stride (floats). 64*101*4 = 25856B -> 6 blocks/CU.
#define MPS 832     // mp stride per (n,o): 26 rows x 32 (rows 0..24 = m[v][u],
                    // row 25 = b3[o]*sum_v m[u][v] for phase-2 acc init)

// NOTE: rounds 3 and 5 both failed on container acquisition (infra), and the
// round-3 resubmission of unchanged source passed. This is an unchanged
// resubmission of the round-5 source (audited: in-bounds, no new sync
// structure, no capture-unsafe calls).

typedef _Float16 f16x8 __attribute__((ext_vector_type(8)));
typedef float f32x16 __attribute__((ext_vector_type(16)));

// ---------------------------------------------------------------------------
// Kernel A: xsum[n][c][v] = sum_t x[n][c][t][v]
// One block per (n,c). float4-stage the plane into LDS, tree reduction.
// Blocks 0..15 also convert w3 -> fp16 (natural [o][c] layout, used as the
// MFMA A-operand in k_fused).
// ---------------------------------------------------------------------------
__global__ __launch_bounds__(256) void k_xsum(const float* __restrict__ x,
                                              float* __restrict__ xsum,
                                              const float* __restrict__ w3,
                                              _Float16* __restrict__ w3h) {
  int nc = blockIdx.x;  // n*64 + c
  int tid = threadIdx.x;
  if (blockIdx.x < 16) {
    int k = blockIdx.x * 256 + tid;  // < 4096, w3 is [o][c] row-major
    w3h[k] = (_Float16)w3[k];
  }
  const float4* src4 = (const float4*)(x + (size_t)nc * PLANE);
  __shared__ __align__(16) float s[PLANE + 256];
  float4* s4 = (float4*)s;
  for (int k = tid; k < PLANE / 4; k += 256) s4[k] = src4[k];
  __syncthreads();
  if (tid < 200) {
    int tg = tid / 25, v = tid - tg * 25;
    float a0 = 0.f, a1 = 0.f, a2 = 0.f, a3 = 0.f;
    for (int k = 0; k < 32; k += 4) {
      a0 += s[(tg + 8 * (k + 0)) * VV + v];
      a1 += s[(tg + 8 * (k + 1)) * VV + v];
      a2 += s[(tg + 8 * (k + 2)) * VV + v];
      a3 += s[(tg + 8 * (k + 3)) * VV + v];
    }
    s[PLANE + tid] = (a0 + a1) + (a2 + a3);
  }
  __syncthreads();
  if (tid < VV) {
    float a = 0.f;
#pragma unroll
    for (int g = 0; g < 8; ++g) a += s[PLANE + g * VV + tid];
    xsum[nc * VV + tid] = a;
  }
}

// ---------------------------------------------------------------------------
// Kernel B: build m, layout mp[n][o][v][32] (word u = m[n,o,u,v]); extra row
// v=25 holds b3[o]*sum_v m[u][v] (phase-2 accumulator init -- this is how b3
// of conv3 enters the output: out = sum_v m*x3' + b3*sum_v m).
// Grid (n, og): each block computes 8 o's.
// ---------------------------------------------------------------------------
__global__ __launch_bounds__(256) void k_build_m(
    const float* __restrict__ xsum, const float* __restrict__ A,
    const float* __restrict__ w1, const float* __restrict__ b1,
    const float* __restrict__ w2, const float* __restrict__ b2,
    const float* __restrict__ b3, const float* __restrict__ w4,
    const float* __restrict__ b4, float* __restrict__ mp) {
  int n = blockIdx.x;
  int og = blockIdx.y;             // o-group: o in [og*8, og*8+8)
  __shared__ float xs[CC * VV];    // 1600
  __shared__ float sx1[RR * VV];   // 200
  __shared__ float sx2[RR * VV];   // 200
  __shared__ float att[RR * 625];  // 5000
  int tid = threadIdx.x;
  const float* xsn = xsum + n * (CC * VV);
  for (int k = tid; k < CC * VV; k += 256) xs[k] = xsn[k];
  __syncthreads();
  if (tid < RR * VV) {
    int r = tid / VV, v = tid % VV;
    float a1 = 0.f, a2 = 0.f;
#pragma unroll
    for (int c = 0; c < CC; ++c) {
      float xv = xs[c * VV + v];
      a1 = fmaf(w1[r * CC + c], xv, a1);
      a2 = fmaf(w2[r * CC + c], xv, a2);
    }
    sx1[tid] = a1 * (1.f / 256.f) + b1[r];
    sx2[tid] = a2 * (1.f / 256.f) + b2[r];
  }
  __syncthreads();
  for (int k = tid; k < RR * 625; k += 256) {
    int r = k / 625, uv = k % 625;
    int u = uv / VV, v = uv % VV;
    att[k] = tanhf(sx1[r * VV + u] - sx2[r * VV + v]);
  }
  __syncthreads();
  for (int k = tid; k < 8 * 625; k += 256) {
    int o = og * 8 + k / 625, vu = k % 625;
    int v = vu / VV, u = vu % VV;
    float a = b4[o] + A[u * VV + v];
#pragma unroll
    for (int r = 0; r < RR; ++r)
      a = fmaf(w4[o * RR + r], att[r * 625 + u * VV + v], a);
    mp[(size_t)(n * OO + o) * MPS + v * 32 + u] = a;
  }
  // b3-fold row: mb3[u] = b3[o] * sum_v m[u][v]. __syncthreads drains vmcnt
  // so this block's mp writes above are visible (same-block readback).
  __syncthreads();
  if (tid < 200) {
    int ol = tid / 25, u = tid % 25;
    int o = og * 8 + ol;
    const float* row = mp + (size_t)(n * OO + o) * MPS;
    float sum = 0.f;
#pragma unroll
    for (int v = 0; v < VV; ++v) sum += row[v * 32 + u];
    mp[(size_t)(n * OO + o) * MPS + 800 + u] = b3[o] * sum;
  }
}

// ---------------------------------------------------------------------------
// Kernel F (fused conv3 + aggregation): block = (t-tile of 4 rows, n).
// Round-4 post-mortem: VALU issue was at the fp32-FMA floor (~43us chip-wide
// for conv3 alone). This version moves conv3 to f16 MFMA:
// Phase 1: per wave (= p-tile of 32 points, P padded 100->128):
//   x3[64o x 32p] = W[64o x 64c] x X[64c x 32p] via 2 o-tiles x 4 k-steps of
//   v_mfma_f32_32x32x16_f16. B-frags load STRAIGHT from global x (lane l:
//   col p = l&31, k-rows c = 8*(l>>5)+e -> each load instr = two contiguous
//   128B segments, no LDS staging); A-frags from fp16 w3h (8KB, L1-hot).
//   C layout (verified m74/m101): col=lane&31, row=(reg&3)+8*(reg>>2)+
//   4*(lane>>5). Writeback to s[o][p] masked to p<100. fp16 quantization
//   error ~1e-3 << 0.03125 tolerance (f32 accumulate, exact f16 products).
// Phase 2: unchanged fp32 (lane (o=tid>>2, uq=tid&3), m rows as float4),
//   except acc inits from mp row 25 (the b3-fold) instead of zero.
// Phase 3: coalesced [64 o][100 p] tile store via LDS.
// ---------------------------------------------------------------------------
__global__ __launch_bounds__(256, 6) void k_fused(
    const float* __restrict__ x, const _Float16* __restrict__ w3h,
    const float* __restrict__ mp, float* __restrict__ out) {
  int n = blockIdx.y;
  int t0 = blockIdx.x * 4;      // 64 tiles of 4 t-rows
  __shared__ float s[OO * SX];  // 25856 B -> 6 blocks/CU
  int tid = threadIdx.x;

  // ---- phase 1: conv3 via MFMA
  {
    int lane = tid & 63;
    int pt = tid >> 6;                  // wave id = p-tile
    int p = pt * 32 + (lane & 31);      // this lane's output column
    int pc = p < 100 ? p : 99;          // clamp pad lanes in-bounds
    int chalf = (lane >> 5) * 8;        // k-row group within a k-step
    const float* xb = x + (size_t)n * CC * PLANE + t0 * VV + pc;
    const _Float16* wa0 = w3h + (lane & 31) * 64 + chalf;        // o-tile 0
    const _Float16* wa1 = w3h + ((lane & 31) + 32) * 64 + chalf; // o-tile 1
    f32x16 acc0 = {0, 0, 0, 0, 0, 0, 0, 0, 0, 0, 0, 0, 0, 0, 0, 0};
    f32x16 acc1 = {0, 0, 0, 0, 0, 0, 0, 0, 0, 0, 0, 0, 0, 0, 0, 0};
#pragma unroll 2
    for (int ks = 0; ks < 4; ++ks) {
      float xv[8];
#pragma unroll
      for (int e = 0; e < 8; ++e)
        xv[e] = xb[(size_t)(ks * 16 + chalf + e) * PLANE];
      f16x8 bf;
#pragma unroll
      for (int e = 0; e < 8; ++e) bf[e] = (_Float16)xv[e];
      f16x8 a0 = *(const f16x8*)(wa0 + ks * 16);
      f16x8 a1 = *(const f16x8*)(wa1 + ks * 16);
      acc0 = __builtin_amdgcn_mfma_f32_32x32x16_f16(a0, bf, acc0, 0, 0, 0);
      acc1 = __builtin_amdgcn_mfma_f32_32x32x16_f16(a1, bf, acc1, 0, 0, 0);
    }
    if (p < 100) {
#pragma unroll
      for (int r = 0; r < 16; ++r) {
        int row = (r & 3) + 8 * (r >> 2) + 4 * (lane >> 5);
        s[row * SX + p] = acc0[r];
        s[(row + 32) * SX + p] = acc1[r];
      }
    }
  }
  __syncthreads();

  // ---- phase 2: out[t][u] = sum_v m[o][u][v] * x3[o][t][v]  (+ b3-fold)
  {
    int o = tid >> 2, uq = tid & 3;
    const float* mb = mp + (size_t)(n * OO + o) * MPS + uq * 8;
    const float* xr = s + o * SX;
    float4 i0 = *(const float4*)(mb + 800);
    float4 i1 = *(const float4*)(mb + 804);
    float acc[4][8];
#pragma unroll
    for (int t = 0; t < 4; ++t) {
      acc[t][0] = i0.x; acc[t][1] = i0.y; acc[t][2] = i0.z; acc[t][3] = i0.w;
      acc[t][4] = i1.x; acc[t][5] = i1.y; acc[t][6] = i1.z; acc[t][7] = i1.w;
    }
#pragma unroll 2
    for (int v = 0; v < VV; ++v) {
      float4 m0 = *(const float4*)(mb + v * 32);
      float4 m1 = *(const float4*)(mb + v * 32 + 4);
      float xt[4];
#pragma unroll
      for (int t = 0; t < 4; ++t) xt[t] = xr[t * VV + v];
#pragma unroll
      for (int t = 0; t < 4; ++t) {
        acc[t][0] = fmaf(m0.x, xt[t], acc[t][0]);
        acc[t][1] = fmaf(m0.y, xt[t], acc[t][1]);
        acc[t][2] = fmaf(m0.z, xt[t], acc[t][2]);
        acc[t][3] = fmaf(m0.w, xt[t], acc[t][3]);
        acc[t][4] = fmaf(m1.x, xt[t], acc[t][4]);
        acc[t][5] = fmaf(m1.y, xt[t], acc[t][5]);
        acc[t][6] = fmaf(m1.z, xt[t], acc[t][6]);
        acc[t][7] = fmaf(m1.w, xt[t], acc[t][7]);
      }
    }
    __syncthreads();  // all phase-2 x3 reads done; reuse s as the out tile
#pragma unroll
    for (int t = 0; t < 4; ++t)
#pragma unroll
      for (int j = 0; j < 8; ++j) {
        int u = uq * 8 + j;
        if (u < VV) s[o * SX + t * VV + u] = acc[t][j];
      }
  }
  __syncthreads();

  // ---- phase 3: coalesced store of the [64 o][100 p] tile
  float* ob = out + (size_t)n * OO * PLANE + t0 * VV;
  for (int k = tid; k < OO * 100; k += 256) {
    int oo = k / 100, p = k - oo * 100;
    ob[(size_t)oo * PLANE + p] = s[oo * SX + p];
  }
}

extern "C" void kernel_launch(void* const* d_in, const int* in_sizes, int n_in,
                              void* d_out, int out_size, void* d_ws,
                              size_t ws_size, hipStream_t stream) {
  const float* x = (const float*)d_in[0];
  const float* A = (const float*)d_in[1];
  const float* w1 = (const float*)d_in[2];
  const float* b1 = (const float*)d_in[3];
  const float* w2 = (const float*)d_in[4];
  const float* b2 = (const float*)d_in[5];
  const float* w3 = (const float*)d_in[6];
  const float* b3 = (const float*)d_in[7];
  const float* w4 = (const float*)d_in[8];
  const float* b4 = (const float*)d_in[9];
  float* out = (float*)d_out;
  float* ws = (float*)d_ws;

  float* xsum = ws;                       // 64*64*25 = 102400 floats
  _Float16* w3h = (_Float16*)(ws + 102400);  // 4096 halfs = 2048 float slots
  float* mp = ws + 102400 + 2048;         // 64*64*832 floats (13.6 MB)

  k_xsum<<<NN * CC, 256, 0, stream>>>(x, xsum, w3, w3h);
  k_build_m<<<dim3(NN, 8), 256, 0, stream>>>(xsum, A, w1, b1, w2, b2, b3, w4,
                                             b4, mp);
  k_fused<<<dim3(TT / 4, NN), 256, 0, stream>>>(x, w3h, mp, out);
}